// Round 6
// baseline (299.560 us; speedup 1.0000x reference)
//
#include <hip/hip_runtime.h>
#include <hip/hip_bf16.h>
#include <stdint.h>

typedef __bf16 bf16_t;
typedef __bf16 bf16x8 __attribute__((ext_vector_type(8)));
typedef __bf16 bf16x4 __attribute__((ext_vector_type(4)));
typedef float f32x4 __attribute__((ext_vector_type(4)));
typedef float f32x4v __attribute__((ext_vector_type(4)));   // for nontemporal builtin

#define Edim 2048
#define Cdim 64
#define Fdim 18
#define Pdim 1024
#define Ntok (Fdim * Pdim)   // 18432
#define KSPLIT 16            // k-chunks for small GEMMs

// convert 8 consecutive f32 at p (16B-aligned) to a bf16x8 fragment
__device__ __forceinline__ bf16x8 cvt8(const float* __restrict__ p) {
    float4 lo = *(const float4*)p;
    float4 hi = *(const float4*)(p + 4);
    bf16x8 r;
    r[0] = (bf16_t)lo.x; r[1] = (bf16_t)lo.y; r[2] = (bf16_t)lo.z; r[3] = (bf16_t)lo.w;
    r[4] = (bf16_t)hi.x; r[5] = (bf16_t)hi.y; r[6] = (bf16_t)hi.z; r[7] = (bf16_t)hi.w;
    return r;
}

// non-temporal variant: X is read-once streaming; don't pollute L2
__device__ __forceinline__ bf16x8 cvt8_nt(const float* __restrict__ p) {
    f32x4v lo = __builtin_nontemporal_load((const f32x4v*)p);
    f32x4v hi = __builtin_nontemporal_load((const f32x4v*)p + 1);
    bf16x8 r;
    r[0] = (bf16_t)lo[0]; r[1] = (bf16_t)lo[1]; r[2] = (bf16_t)lo[2]; r[3] = (bf16_t)lo[3];
    r[4] = (bf16_t)hi[0]; r[5] = (bf16_t)hi[1]; r[6] = (bf16_t)hi[2]; r[7] = (bf16_t)hi[3];
    return r;
}

// ---------------------------------------------------------------------------
// split-K small GEMM: parts[ky][64][2048] = Am[64, kchunk] @ Bm[kchunk, 2048]
// grid = (32 n-tiles, 16 k-chunks of 128), block = 256 (4 waves partition M=64).
// Fully unrolled -> 128 independent B-loads in flight per lane.
// ---------------------------------------------------------------------------
template <bool A_IS_F32>
__global__ __launch_bounds__(256) void splitk_gemm_kernel(
    const void* __restrict__ Am, const float* __restrict__ Bm,
    float* __restrict__ parts)
{
    const int tid  = threadIdx.x;
    const int wave = tid >> 6;
    const int lane = tid & 63;
    const int l15  = lane & 15;
    const int koct = lane >> 4;
    const int n0   = blockIdx.x * 64;
    const int kb   = blockIdx.y * 128;

    f32x4 acc[4] = {};

    #pragma unroll
    for (int i = 0; i < 4; ++i) {
        const int k0 = kb + i * 32;
        bf16x8 a;
        if constexpr (A_IS_F32)
            a = cvt8((const float*)Am + (size_t)(wave * 16 + l15) * Edim + k0 + koct * 8);
        else
            a = *(const bf16x8*)((const bf16_t*)Am + (size_t)(wave * 16 + l15) * Edim + k0 + koct * 8);
        #pragma unroll
        for (int t = 0; t < 4; ++t) {
            const float* src = Bm + (size_t)(k0 + koct * 8) * Edim + n0 + t * 16 + l15;
            bf16x8 b;
            #pragma unroll
            for (int j = 0; j < 8; ++j) b[j] = (bf16_t)src[(size_t)j * Edim];
            acc[t] = __builtin_amdgcn_mfma_f32_16x16x32_bf16(a, b, acc[t], 0, 0, 0);
        }
    }

    float* dst = parts + (size_t)blockIdx.y * (Cdim * Edim);
    #pragma unroll
    for (int t = 0; t < 4; ++t) {
        #pragma unroll
        for (int r = 0; r < 4; ++r) {
            int m = wave * 16 + koct * 4 + r;   // C/D row = (lane>>4)*4 + reg
            int n = n0 + t * 16 + l15;          // C/D col = lane&15
            dst[(size_t)m * Edim + n] = acc[t][r];
        }
    }
}

// ---------------------------------------------------------------------------
// Fused reduce + bias. grid = 64 (one block per row c), block = 256.
// A_f32[c,k] = sum_j parts[j][c][k]; A_bf row written out; and
// beff[c] = 0.75*( A_f32[c,:]·bv + Wmp[c,:]·bo ) + bmp[c].
// ---------------------------------------------------------------------------
__global__ __launch_bounds__(256) void reduce_bias_kernel(
    const float* __restrict__ parts, const float* __restrict__ Wmp,
    const float* __restrict__ bv, const float* __restrict__ bo,
    const float* __restrict__ bmp,
    bf16_t* __restrict__ A_bf, float* __restrict__ beff)
{
    const int c   = blockIdx.x;
    const int tid = threadIdx.x;
    const int col = tid * 8;

    float4 s0 = {0.f, 0.f, 0.f, 0.f}, s1 = {0.f, 0.f, 0.f, 0.f};
    #pragma unroll
    for (int j = 0; j < KSPLIT; ++j) {
        const float* p = parts + (size_t)j * (Cdim * Edim) + (size_t)c * Edim + col;
        float4 v0 = *(const float4*)p;
        float4 v1 = *(const float4*)(p + 4);
        s0.x += v0.x; s0.y += v0.y; s0.z += v0.z; s0.w += v0.w;
        s1.x += v1.x; s1.y += v1.y; s1.z += v1.z; s1.w += v1.w;
    }

    bf16x8 r;
    r[0] = (bf16_t)s0.x; r[1] = (bf16_t)s0.y; r[2] = (bf16_t)s0.z; r[3] = (bf16_t)s0.w;
    r[4] = (bf16_t)s1.x; r[5] = (bf16_t)s1.y; r[6] = (bf16_t)s1.z; r[7] = (bf16_t)s1.w;
    *(bf16x8*)(A_bf + (size_t)c * Edim + col) = r;

    float4 b0 = *(const float4*)(bv + col);
    float4 b1 = *(const float4*)(bv + col + 4);
    float4 w0 = *(const float4*)(Wmp + (size_t)c * Edim + col);
    float4 w1 = *(const float4*)(Wmp + (size_t)c * Edim + col + 4);
    float4 o0 = *(const float4*)(bo + col);
    float4 o1 = *(const float4*)(bo + col + 4);

    float s = s0.x * b0.x + s0.y * b0.y + s0.z * b0.z + s0.w * b0.w
            + s1.x * b1.x + s1.y * b1.y + s1.z * b1.z + s1.w * b1.w
            + w0.x * o0.x + w0.y * o0.y + w0.z * o0.z + w0.w * o0.w
            + w1.x * o1.x + w1.y * o1.y + w1.z * o1.z + w1.w * o1.w;

    #pragma unroll
    for (int off = 32; off > 0; off >>= 1) s += __shfl_down(s, off);

    __shared__ float red[4];
    if ((tid & 63) == 0) red[tid >> 6] = s;
    __syncthreads();
    if (tid == 0)
        beff[c] = 0.75f * (red[0] + red[1] + red[2] + red[3]) + bmp[c];
}

// ---------------------------------------------------------------------------
// out_bf16[i] = scale * sum_{j<16} parts[j][i]   (131072 elems; grid 128 x 256)
// ---------------------------------------------------------------------------
__global__ __launch_bounds__(256) void reduce_parts_kernel(
    const float* __restrict__ parts, bf16_t* __restrict__ out, float scale)
{
    const int idx = (blockIdx.x * 256 + threadIdx.x) * 4;
    float4 s = {0.f, 0.f, 0.f, 0.f};
    #pragma unroll
    for (int j = 0; j < KSPLIT; ++j) {
        float4 v = *(const float4*)(parts + (size_t)j * (Cdim * Edim) + idx);
        s.x += v.x; s.y += v.y; s.z += v.z; s.w += v.w;
    }
    bf16x4 r;
    r[0] = (bf16_t)(scale * s.x); r[1] = (bf16_t)(scale * s.y);
    r[2] = (bf16_t)(scale * s.z); r[3] = (bf16_t)(scale * s.w);
    *(bf16x4*)(out + idx) = r;
}

// ---------------------------------------------------------------------------
// main GEMM: out[(p*F+f)*64+c] = X[n,:]·Weff[c,:] + b_eff[c],  n = f*P+p
// M=32 per block (2 row-tiles/wave), split-K x4 across waves, grid = 576.
// Non-temporal X loads; all-wave LDS reduce; wave w stores column-tile t=w.
// ---------------------------------------------------------------------------
__global__ __launch_bounds__(256, 2) void main_gemm_kernel(
    const float* __restrict__ X, const bf16_t* __restrict__ Weff,
    const float* __restrict__ b_eff, float* __restrict__ out)
{
    __shared__ float red[4 * 64 * 33];   // 4 waves x 64 lanes x 32 vals (+1 pad)

    const int tid  = threadIdx.x;
    const int wave = tid >> 6;
    const int lane = tid & 63;
    const int l15  = lane & 15;
    const int koct = lane >> 4;

    const int rbase = blockIdx.x * 32;
    const float* x0 = X + (size_t)(rbase + l15) * Edim;
    const float* x1 = x0 + (size_t)16 * Edim;
    const int kbase = wave * 512;

    f32x4 acc[2][4] = {};

    #pragma unroll 8
    for (int k0 = kbase; k0 < kbase + 512; k0 += 32) {
        bf16x8 a0 = cvt8_nt(x0 + k0 + koct * 8);
        bf16x8 a1 = cvt8_nt(x1 + k0 + koct * 8);
        #pragma unroll
        for (int t = 0; t < 4; ++t) {
            bf16x8 b = *(const bf16x8*)(Weff + (size_t)(t * 16 + l15) * Edim + k0 + koct * 8);
            acc[0][t] = __builtin_amdgcn_mfma_f32_16x16x32_bf16(a0, b, acc[0][t], 0, 0, 0);
            acc[1][t] = __builtin_amdgcn_mfma_f32_16x16x32_bf16(a1, b, acc[1][t], 0, 0, 0);
        }
    }

    // all waves dump accumulators to LDS
    {
        float* dst = &red[wave * 2112 + lane * 33];
        #pragma unroll
        for (int e = 0; e < 2; ++e)
            #pragma unroll
            for (int t = 0; t < 4; ++t)
                #pragma unroll
                for (int r = 0; r < 4; ++r) dst[e * 16 + t * 4 + r] = acc[e][t][r];
    }
    __syncthreads();

    // wave w reduces across the 4 k-quarters and stores column-tile t = w
    {
        const int c  = wave * 16 + l15;
        const float be = b_eff[c];
        #pragma unroll
        for (int e = 0; e < 2; ++e) {
            #pragma unroll
            for (int r = 0; r < 4; ++r) {
                float v = 0.f;
                #pragma unroll
                for (int ws = 0; ws < 4; ++ws)
                    v += red[ws * 2112 + lane * 33 + e * 16 + wave * 4 + r];
                const int m = rbase + e * 16 + koct * 4 + r;
                const int f = m >> 10;          // n / 1024
                const int p = m & 1023;         // n % 1024
                out[(size_t)(p * Fdim + f) * Cdim + c] = v + be;
            }
        }
    }
}

// ---------------------------------------------------------------------------
extern "C" void kernel_launch(void* const* d_in, const int* in_sizes, int n_in,
                              void* d_out, int out_size, void* d_ws, size_t ws_size,
                              hipStream_t stream)
{
    // setup_inputs order: emb, Wq, Wk, Wv, bq, bk, bv, Wo, bo, Wmp, bmp (all f32)
    const float* emb = (const float*)d_in[0];
    const float* Wv  = (const float*)d_in[3];
    const float* bv  = (const float*)d_in[6];
    const float* Wo  = (const float*)d_in[7];
    const float* bo  = (const float*)d_in[8];
    const float* Wmp = (const float*)d_in[9];
    const float* bmp = (const float*)d_in[10];

    const size_t PART = (size_t)Cdim * Edim;                     // 131072
    float*  parts1 = (float*)d_ws;                               // [16][64][2048] f32 (8 MB)
    float*  parts2 = parts1 + (size_t)KSPLIT * PART;             // 8 MB
    bf16_t* A_bf   = (bf16_t*)(parts2 + (size_t)KSPLIT * PART);  // [64,2048] bf16
    bf16_t* Weffb  = A_bf + PART;                                // [64,2048] bf16
    float*  beff   = (float*)(Weffb + PART);                     // [64] f32

    float* out = (float*)d_out;

    // A partials = Wmp @ Wo (split-K x16)
    splitk_gemm_kernel<true><<<dim3(32, KSPLIT), 256, 0, stream>>>(Wmp, Wo, parts1);
    // A_bf = bf16(sum parts1); beff = 0.75*(A·bv + Wmp·bo) + bmp
    reduce_bias_kernel<<<64, 256, 0, stream>>>(parts1, Wmp, bv, bo, bmp, A_bf, beff);
    // Weff partials = A @ Wv (split-K x16)
    splitk_gemm_kernel<false><<<dim3(32, KSPLIT), 256, 0, stream>>>(A_bf, Wv, parts2);
    // Weffb = bf16(0.75 * sum parts2)
    reduce_parts_kernel<<<128, 256, 0, stream>>>(parts2, Weffb, 0.75f);
    // out = X @ Weff^T + b_eff  (+ output row permutation)
    main_gemm_kernel<<<Ntok / 32, 256, 0, stream>>>(emb, Weffb, beff, out);
}